// Round 2
// baseline (246.896 us; speedup 1.0000x reference)
//
#include <hip/hip_runtime.h>
#include <cfloat>
#include <cmath>

#define DEVINL __device__ __forceinline__

constexpr int N_ = 4, C_ = 21, H_ = 512, W_ = 512;
constexpr int P_ = 171;           // pooled H/W
constexpr int Q_ = 169;           // point grid: P-3+1
constexpr int NC_ = N_ * C_;      // 84
constexpr int HW_ = H_ * W_;      // 262144 = 2^18
constexpr int PROW_ = 172;        // padded row stride for pr/la (16B-aligned rows)
constexpr int PPAD_ = PROW_ * P_; // 29412 per (n,c) image
constexpr int NCOV_ = 189;        // 9 + 9 + 45 + 45 + 81
constexpr float EPS_ = 5e-4f;
constexpr int RC_ = 29;           // rows per k_cov chunk (6 chunks cover 169)
constexpr int G_ = 43;            // col-quads per row

DEVINL constexpr int tstart(int d) { return d * 9 - d * (d - 1) / 2; }

DEVINL float wave_sum(float v) {
#pragma unroll
    for (int o = 32; o > 0; o >>= 1) v += __shfl_down(v, o, 64);
    return v;
}

// ---------------------------------------------------------------------------
// do_cell: masked 3x3 max + sigmoid + clip for one pooled cell (from k_pool).
// ---------------------------------------------------------------------------
template <int IDX>
DEVINL void do_cell(const float (&f)[3][16], unsigned pk, int c, float* prp, float* lap) {
    unsigned px = pk >> 23;
    float vm = -FLT_MAX;
#pragma unroll
    for (int r = 0; r < 3; ++r)
#pragma unroll
        for (int dc = 0; dc < 3; ++dc)
            vm = fmaxf(vm, ((px >> (r * 3 + dc)) & 1u) ? f[r][IDX + dc] : -FLT_MAX);
    float p = __builtin_amdgcn_rcpf(1.f + __expf(-vm));
    p = fminf(fmaxf(p, 1e-6f), 1.f);
    *prp = p;
    *lap = ((pk >> c) & 1u) ? 1.f : 0.f;
}

// ---------------------------------------------------------------------------
// k_fused v2: block = (half, pooled-row i, n), 256 threads.
// R1 post-mortem: VGPR=40 proved the compiler sank the 21 float4 CE loads to
// their uses -> serialized HBM latency chain (1.67 TB/s, VALUBusy 12%). Fixes:
//  - Phase A: loads batched 7-at-a-time behind an asm memory fence so 7 HBM
//    loads are in flight per thread (compiler cannot sink across the clobber).
//  - Phase B now runs on wave 3 CONCURRENTLY with waves 0-2's CE.
//  - Phase C vectorized like old k_pool: 12 float4 L1 loads per 4 cells
//    (was 36 scalar strided loads); exactly 2 items per thread.
// Cell split: half0 = cells 0..87 (groups 0..21), half1 = 88..170 (22..42)
// so col-groups of 4 never straddle the block boundary.
// ---------------------------------------------------------------------------
__global__ __launch_bounds__(256) void k_fused(const float* __restrict__ score,
                                               const int* __restrict__ target,
                                               float* __restrict__ pr,
                                               float* __restrict__ la,
                                               float* __restrict__ cov) {
    __shared__ unsigned sh_pack[88];
    __shared__ float rn[4], rc[4];
    int half = blockIdx.x;
    int i = blockIdx.y;
    int n = blockIdx.z;
    int t = threadIdx.x;
    int wv = t >> 6, lane = t & 63;
    int c0 = half * 256;                 // owned CE columns [c0, c0+256)
    int jlo = half ? 88 : 0;             // owned pooled cells [jlo, jlo+ncell)
    int ncell = half ? 83 : 88;
    int glo = half ? 22 : 0;             // owned col-groups [glo, glo+gn)
    int gn = half ? 21 : 22;

    int hl = 3 * i - 1; if (hl < 0) hl = 0;
    int rowbase = (i == 0) ? 0 : 3 * i - 1;
    int nrows = (i == 0) ? 2 : 3;

    // ---- Phase A (waves 0-2): CE | Phase B (wave 3): pack bits, concurrent --
    float nll = 0.f, cnt = 0.f;
    if (wv < 3) {
        if (wv < nrows) {
            int row = rowbase + wv;
            size_t pixoff = (size_t)row * W_ + c0 + 4 * lane;
            const float* sp = score + (size_t)n * C_ * HW_ + pixoff;
            int4 t4 = *(const int4*)(target + (size_t)n * HW_ + pixoff);

            float4 se = {0.f, 0.f, 0.f, 0.f};
            float4 stgt = {0.f, 0.f, 0.f, 0.f};
            float4 s[7];
#pragma unroll
            for (int cb = 0; cb < C_; cb += 7) {
#pragma unroll
                for (int u = 0; u < 7; ++u)
                    s[u] = *(const float4*)(sp + (size_t)(cb + u) * HW_);
                asm volatile("" ::: "memory");  // keep 7 loads in flight
#pragma unroll
                for (int u = 0; u < 7; ++u) {
                    int c = cb + u;
                    se.x += __expf(s[u].x);
                    se.y += __expf(s[u].y);
                    se.z += __expf(s[u].z);
                    se.w += __expf(s[u].w);
                    if (t4.x == c) stgt.x = s[u].x;
                    if (t4.y == c) stgt.y = s[u].y;
                    if (t4.z == c) stgt.z = s[u].z;
                    if (t4.w == c) stgt.w = s[u].w;
                }
            }
            if (t4.x != 255) { nll += __logf(se.x) - stgt.x; cnt += 1.f; }
            if (t4.y != 255) { nll += __logf(se.y) - stgt.y; cnt += 1.f; }
            if (t4.z != 255) { nll += __logf(se.z) - stgt.z; cnt += 1.f; }
            if (t4.w != 255) { nll += __logf(se.w) - stgt.w; cnt += 1.f; }
        }
    } else {
        for (int idx = lane; idx < ncell; idx += 64) {
            int j = jlo + idx;
            int wl = 3 * j - 1; if (wl < 0) wl = 0;
            int hmax = 3 * i + 1, wmax = 3 * j + 1;
            const int* tb = target + (size_t)n * HW_;
            unsigned oh = 0, px = 0;
#pragma unroll
            for (int r = 0; r < 3; ++r) {
                int hh = hl + r;
                bool hv = hh <= hmax;
                const int* trow = tb + hh * W_;
#pragma unroll
                for (int dc = 0; dc < 3; ++dc) {
                    int ww = wl + dc;
                    int tv = trow[ww];
                    if (hv && (ww <= wmax) && tv >= 0 && tv < C_) {
                        oh |= 1u << tv;
                        px |= 1u << (r * 3 + dc);
                    }
                }
            }
            sh_pack[idx] = oh | (px << 23);
        }
    }
    nll = wave_sum(nll);
    cnt = wave_sum(cnt);
    if (lane == 0) { rn[wv] = nll; rc[wv] = cnt; }
    __syncthreads();
    if (t == 0)
        atomicAdd(&cov[NC_ * NCOV_ + 0], rn[0] + rn[1] + rn[2] + rn[3]);
    if (t == 64)
        atomicAdd(&cov[NC_ * NCOV_ + 1], rc[0] + rc[1] + rc[2] + rc[3]);

    // ---- Phase C: pooling over (class, col-group) items; L1/L2-hot reads ----
    int nitems = C_ * gn;   // 462 (half0) / 441 (half1): exactly 2 per thread
    for (int it = t; it < nitems; it += 256) {
        int c = it / gn;
        int gg = it - c * gn;
        int g = glo + gg;
        int b = (g == 0) ? 0 : 12 * g - 4;
        int o3 = (b + 15 < W_) ? 12 : 8;
        int ncidx = n * C_ + c;
        const float* sb = score + (size_t)ncidx * HW_ + (size_t)hl * W_ + b;
        float f[3][16];
#pragma unroll
        for (int r = 0; r < 3; ++r) {
            const float* rp = sb + r * W_;
            float4 q0 = *(const float4*)(rp);
            float4 q1 = *(const float4*)(rp + 4);
            float4 q2 = *(const float4*)(rp + 8);
            float4 q3 = *(const float4*)(rp + o3);
            f[r][0] = q0.x;  f[r][1] = q0.y;  f[r][2] = q0.z;  f[r][3] = q0.w;
            f[r][4] = q1.x;  f[r][5] = q1.y;  f[r][6] = q1.z;  f[r][7] = q1.w;
            f[r][8] = q2.x;  f[r][9] = q2.y;  f[r][10] = q2.z; f[r][11] = q2.w;
            f[r][12] = q3.x; f[r][13] = q3.y; f[r][14] = q3.z; f[r][15] = q3.w;
        }
        int sb0 = 4 * g - jlo;   // sh_pack index of cell 4g
        size_t ob = (size_t)ncidx * PPAD_ + (size_t)i * PROW_ + 4 * g;
        if (g == 0) {
            do_cell<0>(f, sh_pack[sb0 + 0], c, pr + ob + 0, la + ob + 0);
            do_cell<2>(f, sh_pack[sb0 + 1], c, pr + ob + 1, la + ob + 1);
            do_cell<5>(f, sh_pack[sb0 + 2], c, pr + ob + 2, la + ob + 2);
            do_cell<8>(f, sh_pack[sb0 + 3], c, pr + ob + 3, la + ob + 3);
        } else {
            do_cell<3>(f, sh_pack[sb0 + 0], c, pr + ob + 0, la + ob + 0);
            do_cell<6>(f, sh_pack[sb0 + 1], c, pr + ob + 1, la + ob + 1);
            do_cell<9>(f, sh_pack[sb0 + 2], c, pr + ob + 2, la + ob + 2);
            if (4 * g + 3 < P_)
                do_cell<12>(f, sh_pack[sb0 + 3], c, pr + ob + 3, la + ob + 3);
        }
    }
}

// ---------------------------------------------------------------------------
// k_cov v4: 7 register-light parts (<=33 accumulators each). UNCHANGED.
//   z=0: la  s1[9] + SAA d<3 (24)     z=1: la  SAA d>=3 (21)
//   z=2: pr  s1[9] + SBB d<3 (24)     z=3: pr  SBB d>=3 (21)
//   z=4..6: SAB with a-row RA=z-4 (27 each)
// grid = (84, 6, 7), block = 256.
// ---------------------------------------------------------------------------
template <bool WITH_S1, int D0, int D1>
DEVINL void cov_tri(const float* __restrict__ X, float* __restrict__ cov,
                    int nc, int r0, int rend, int s1base, int s2base,
                    int tid, float (*red)[33]) {
    constexpr int NS2 = ((9 - D0) * (10 - D0) - (9 - D1) * (10 - D1)) / 2;
    constexpr int RLO = D0 / 3;
    constexpr int NS1 = WITH_S1 ? 9 : 0;
    constexpr int KOFF = tstart(D0);
    float s1[9], s2[NS2];
#pragma unroll
    for (int k = 0; k < 9; ++k) s1[k] = 0.f;
#pragma unroll
    for (int k = 0; k < NS2; ++k) s2[k] = 0.f;

    int nitems = (rend - r0) * G_;
    for (int idx = tid; idx < nitems; idx += 256) {
        int lr = idx / G_;
        int q = idx - lr * G_;
        int x0 = q * 4;
        const float* base = X + (size_t)(r0 + lr) * PROW_ + x0;
        float v[3][8];
#pragma unroll
        for (int r = RLO; r < 3; ++r) {
            float4 u0 = *(const float4*)(base + r * PROW_);
            float4 u1 = *(const float4*)(base + r * PROW_ + 4);
            v[r][0] = u0.x; v[r][1] = u0.y; v[r][2] = u0.z; v[r][3] = u0.w;
            v[r][4] = u1.x; v[r][5] = u1.y; v[r][6] = u1.z; v[r][7] = u1.w;
        }
#pragma unroll
        for (int p = 0; p < 4; ++p) {
            if (x0 + p < Q_) {
                if constexpr (WITH_S1) {
#pragma unroll
                    for (int d = 0; d < 9; ++d) s1[d] += v[d / 3][p + d % 3];
                }
                int k = 0;
#pragma unroll
                for (int d = D0; d < D1; ++d)
#pragma unroll
                    for (int e = d; e < 9; ++e) {
                        s2[k] += v[d / 3][p + d % 3] * v[e / 3][p + e % 3];
                        ++k;
                    }
            }
        }
    }

    int lane = tid & 63, wv = tid >> 6;
    if constexpr (WITH_S1) {
#pragma unroll
        for (int k = 0; k < 9; ++k) { float v2 = wave_sum(s1[k]); if (lane == 0) red[wv][k] = v2; }
    }
#pragma unroll
    for (int k = 0; k < NS2; ++k) { float v2 = wave_sum(s2[k]); if (lane == 0) red[wv][NS1 + k] = v2; }
    __syncthreads();
    for (int k = tid; k < NS1 + NS2; k += 256) {
        float v2 = red[0][k] + red[1][k] + red[2][k] + red[3][k];
        int dst = (WITH_S1 && k < 9) ? (s1base + k) : (s2base + KOFF + k - NS1);
        atomicAdd(&cov[nc * NCOV_ + dst], v2);
    }
}

template <int RA>
DEVINL void cov_ab(const float* __restrict__ A, const float* __restrict__ B,
                   float* __restrict__ cov, int nc, int r0, int rend,
                   int tid, float (*red)[33]) {
    float sab[27];
#pragma unroll
    for (int k = 0; k < 27; ++k) sab[k] = 0.f;

    int nitems = (rend - r0) * G_;
    for (int idx = tid; idx < nitems; idx += 256) {
        int lr = idx / G_;
        int q = idx - lr * G_;
        int x0 = q * 4;
        size_t off = (size_t)(r0 + lr) * PROW_ + x0;
        float a[8], b[3][8];
        {
            float4 u0 = *(const float4*)(A + off + RA * PROW_);
            float4 u1 = *(const float4*)(A + off + RA * PROW_ + 4);
            a[0] = u0.x; a[1] = u0.y; a[2] = u0.z; a[3] = u0.w;
            a[4] = u1.x; a[5] = u1.y; a[6] = u1.z; a[7] = u1.w;
        }
#pragma unroll
        for (int r = 0; r < 3; ++r) {
            float4 w0 = *(const float4*)(B + off + r * PROW_);
            float4 w1 = *(const float4*)(B + off + r * PROW_ + 4);
            b[r][0] = w0.x; b[r][1] = w0.y; b[r][2] = w0.z; b[r][3] = w0.w;
            b[r][4] = w1.x; b[r][5] = w1.y; b[r][6] = w1.z; b[r][7] = w1.w;
        }
#pragma unroll
        for (int p = 0; p < 4; ++p) {
            if (x0 + p < Q_) {
#pragma unroll
                for (int dm = 0; dm < 3; ++dm)
#pragma unroll
                    for (int e = 0; e < 9; ++e)
                        sab[dm * 9 + e] += a[p + dm] * b[e / 3][p + e % 3];
            }
        }
    }

    int lane = tid & 63, wv = tid >> 6;
#pragma unroll
    for (int k = 0; k < 27; ++k) { float v2 = wave_sum(sab[k]); if (lane == 0) red[wv][k] = v2; }
    __syncthreads();
    for (int k = tid; k < 27; k += 256) {
        float v2 = red[0][k] + red[1][k] + red[2][k] + red[3][k];
        atomicAdd(&cov[nc * NCOV_ + 108 + RA * 27 + k], v2);
    }
}

__global__ __launch_bounds__(256) void k_cov(const float* __restrict__ la,
                                             const float* __restrict__ pr,
                                             float* __restrict__ cov) {
    __shared__ float red[4][33];
    int nc = blockIdx.x;
    int chunk = blockIdx.y;
    int part = blockIdx.z;
    int r0 = chunk * RC_;
    int rend = r0 + RC_;
    if (rend > Q_) rend = Q_;
    int tid = threadIdx.x;
    const float* LA = la + (size_t)nc * PPAD_;
    const float* PR = pr + (size_t)nc * PPAD_;

    switch (part) {
        case 0: cov_tri<true, 0, 3>(LA, cov, nc, r0, rend, 0, 18, tid, red); break;
        case 1: cov_tri<false, 3, 9>(LA, cov, nc, r0, rend, 0, 18, tid, red); break;
        case 2: cov_tri<true, 0, 3>(PR, cov, nc, r0, rend, 9, 63, tid, red); break;
        case 3: cov_tri<false, 3, 9>(PR, cov, nc, r0, rend, 9, 63, tid, red); break;
        case 4: cov_ab<0>(LA, PR, cov, nc, r0, rend, tid, red); break;
        case 5: cov_ab<1>(LA, PR, cov, nc, r0, rend, tid, red); break;
        case 6: cov_ab<2>(LA, PR, cov, nc, r0, rend, tid, red); break;
    }
}

// ---------------------------------------------------------------------------
// k_final: per-(n,c) 9x9 algebra. UNCHANGED.
// ---------------------------------------------------------------------------
__global__ __launch_bounds__(128) void k_final(const float* __restrict__ cov,
                                               float* __restrict__ out) {
    __shared__ float red[128];
    int t = threadIdx.x;
    float my = 0.f;
    if (t < NC_) {
        const float* S = cov + t * NCOV_;
        const float Lf = (float)(Q_ * Q_);  // 28561
        float sA[9], sB[9];
#pragma unroll
        for (int d = 0; d < 9; ++d) { sA[d] = S[d]; sB[d] = S[9 + d]; }
        float laC[45], M[45], Cm[81];
        {
            int k = 0;
#pragma unroll
            for (int d = 0; d < 9; ++d)
#pragma unroll
                for (int e = d; e < 9; ++e) {
                    laC[k] = S[18 + k] - sA[d] * sA[e] / Lf;
                    M[k] = S[63 + k] - sB[d] * sB[e] / Lf + (d == e ? EPS_ : 0.f);
                    ++k;
                }
#pragma unroll
            for (int d = 0; d < 9; ++d)
#pragma unroll
                for (int e = 0; e < 9; ++e)
                    Cm[d * 9 + e] = S[108 + d * 9 + e] - sA[d] * sB[e] / Lf;
        }
#pragma unroll
        for (int j = 0; j < 9; ++j) {
            float s = M[tstart(j)];
#pragma unroll
            for (int k = 0; k < j; ++k) { float l = M[tstart(k) + (j - k)]; s -= l * l; }
            float dj = sqrtf(fmaxf(s, 1e-30f));
            M[tstart(j)] = dj;
            float inv = 1.f / dj;
#pragma unroll
            for (int i = j + 1; i < 9; ++i) {
                float s2 = M[tstart(j) + (i - j)];
#pragma unroll
                for (int k = 0; k < j; ++k)
                    s2 -= M[tstart(k) + (i - k)] * M[tstart(k) + (j - k)];
                M[tstart(j) + (i - j)] = s2 * inv;
            }
        }
#pragma unroll
        for (int p = 0; p < 9; ++p) {
#pragma unroll
            for (int i = 0; i < 9; ++i) {
                float s = Cm[p * 9 + i];
#pragma unroll
                for (int k = 0; k < i; ++k)
                    s -= M[tstart(k) + (i - k)] * Cm[p * 9 + k];
                Cm[p * 9 + i] = s / M[tstart(i)];
            }
        }
#pragma unroll
        for (int d = 0; d < 9; ++d)
#pragma unroll
            for (int e = d; e < 9; ++e) {
                float s = 0.f;
#pragma unroll
                for (int i = 0; i < 9; ++i) s += Cm[d * 9 + i] * Cm[e * 9 + i];
                laC[tstart(d) + (e - d)] -= s;
                if (d == e) laC[tstart(d)] += EPS_;
            }
        float rmi = 0.f;
#pragma unroll
        for (int j = 0; j < 9; ++j) {
            float s = laC[tstart(j)];
#pragma unroll
            for (int k = 0; k < j; ++k) { float l = laC[tstart(k) + (j - k)]; s -= l * l; }
            float dj = sqrtf(fmaxf(s, 0.f));
            laC[tstart(j)] = dj;
            float inv = 1.f / fmaxf(dj, 1e-30f);
#pragma unroll
            for (int i = j + 1; i < 9; ++i) {
                float s2 = laC[tstart(j) + (i - j)];
#pragma unroll
                for (int k = 0; k < j; ++k)
                    s2 -= laC[tstart(k) + (i - k)] * laC[tstart(k) + (j - k)];
                laC[tstart(j) + (i - j)] = s2 * inv;
            }
            rmi += __logf(dj + 1e-8f);
        }
        my = rmi;
    }
    red[t] = my;
    __syncthreads();
#pragma unroll
    for (int o = 64; o > 0; o >>= 1) {
        if (t < o) red[t] += red[t + o];
        __syncthreads();
    }
    if (t == 0) {
        float rmi_total = red[0] / 36.f;  // / (N * HALF_D)
        float ce = cov[NC_ * NCOV_ + 0] / cov[NC_ * NCOV_ + 1];
        out[0] = 0.5f * ce + 0.5f * rmi_total;
    }
}

extern "C" void kernel_launch(void* const* d_in, const int* in_sizes, int n_in,
                              void* d_out, int out_size, void* d_ws, size_t ws_size,
                              hipStream_t stream) {
    const float* score = (const float*)d_in[0];
    const int* target = (const int*)d_in[1];
    float* pr = (float*)d_ws;
    float* la = pr + (size_t)NC_ * PPAD_;
    float* cov = la + (size_t)NC_ * PPAD_;              // NC_*NCOV_ + 2 floats
    hipMemsetAsync(cov, 0, (size_t)(NC_ * NCOV_ + 2) * sizeof(float), stream);

    k_fused<<<dim3(2, P_, N_), dim3(256), 0, stream>>>(score, target, pr, la, cov);
    k_cov<<<dim3(NC_, 6, 7), dim3(256), 0, stream>>>(la, pr, cov);
    k_final<<<dim3(1), dim3(128), 0, stream>>>(cov, (float*)d_out);
}

// Round 3
// 243.971 us; speedup vs baseline: 1.0120x; 1.0120x over previous
//
#include <hip/hip_runtime.h>
#include <cfloat>
#include <cmath>

#define DEVINL __device__ __forceinline__

constexpr int N_ = 4, C_ = 21, H_ = 512, W_ = 512;
constexpr int P_ = 171;           // pooled H/W
constexpr int Q_ = 169;           // point grid: P-3+1
constexpr int NC_ = N_ * C_;      // 84
constexpr int HW_ = H_ * W_;      // 262144 = 2^18
constexpr int PP_ = 29241;        // P_*P_ (pack layout, unpadded)
constexpr int PROW_ = 172;        // padded row stride for pr/la (16B-aligned rows)
constexpr int PPAD_ = PROW_ * P_; // 29412 per (n,c) image
constexpr int NCOV_ = 189;        // 9 + 9 + 45 + 45 + 81
constexpr float EPS_ = 5e-4f;
constexpr int RC_ = 29;           // rows per k_cov chunk (6 chunks cover 169)
constexpr int G_ = 43;            // col-quads per row

constexpr int NB_CE = N_ * HW_ / 4 / 256;            // 1024 CE blocks
constexpr int NB_PL = (NC_ * P_ * G_ + 255) / 256;   // 2413 pool blocks

DEVINL constexpr int tstart(int d) { return d * 9 - d * (d - 1) / 2; }

DEVINL float wave_sum(float v) {
#pragma unroll
    for (int o = 32; o > 0; o >>= 1) v += __shfl_down(v, o, 64);
    return v;
}

// ---------------------------------------------------------------------------
// k_bits: thread per pooled cell (n,i,j) -> packed one-hot + validity bits.
// (R0-verified version, restored: pool role reads pack from global.)
// ---------------------------------------------------------------------------
__global__ __launch_bounds__(256) void k_bits(const int* __restrict__ target,
                                              unsigned* __restrict__ pack) {
    int tid = blockIdx.x * 256 + threadIdx.x;
    if (tid >= N_ * PP_) return;
    int cell = tid % PP_;
    int n = tid / PP_;
    int j = cell % P_;
    int i = cell / P_;
    int hl = 3 * i - 1; if (hl < 0) hl = 0;
    int wl = 3 * j - 1; if (wl < 0) wl = 0;
    int hmax = 3 * i + 1, wmax = 3 * j + 1;
    const int* tb = target + (size_t)n * HW_;
    unsigned oh = 0, px = 0;
#pragma unroll
    for (int r = 0; r < 3; ++r) {
        int hh = hl + r;
        bool hv = hh <= hmax;
        const int* trow = tb + hh * W_;
#pragma unroll
        for (int dc = 0; dc < 3; ++dc) {
            int ww = wl + dc;
            int t = trow[ww];
            if (hv && (ww <= wmax) && t >= 0 && t < C_) {
                oh |= 1u << t;
                px |= 1u << (r * 3 + dc);
            }
        }
    }
    pack[tid] = oh | (px << 23);
}

// ---------------------------------------------------------------------------
// do_cell: masked 3x3 max + sigmoid + clip for one pooled cell.
// ---------------------------------------------------------------------------
template <int IDX>
DEVINL void do_cell(const float (&f)[3][16], unsigned pk, int c, float* prp, float* lap) {
    unsigned px = pk >> 23;
    float vm = -FLT_MAX;
#pragma unroll
    for (int r = 0; r < 3; ++r)
#pragma unroll
        for (int dc = 0; dc < 3; ++dc)
            vm = fmaxf(vm, ((px >> (r * 3 + dc)) & 1u) ? f[r][IDX + dc] : -FLT_MAX);
    float p = __builtin_amdgcn_rcpf(1.f + __expf(-vm));
    p = fminf(fmaxf(p, 1e-6f), 1.f);
    *prp = p;
    *lap = ((pk >> c) & 1u) ? 1.f : 0.f;
}

// ---------------------------------------------------------------------------
// k_mix: CE and pool as ROLE-SPLIT BLOCKS of one kernel (no data dependency
// between them). R2 post-mortem: phase-fusion inside a block serialized the
// two latency-bound phases behind __syncthreads; all pipes idle (VALU 12.6%,
// BW 22%, occ 47%). Here blocks 0..NB_CE-1 run the R0-verified k_ce body,
// blocks NB_CE.. run the R0-verified k_pool body; the scheduler interleaves
// their waves on each SIMD so each role's stall windows are filled by the
// other. 3437 blocks also lifts the wave-occupancy cap from 67% to ~100%.
// CE loads are batched 7-at-a-time behind sched_barrier(0) -- the rule-#18
// fence that actually blocks register-op reordering ("memory" clobber does
// not; proven by VGPR 40->36 in R2).
// ---------------------------------------------------------------------------
__global__ __launch_bounds__(256) void k_mix(const float* __restrict__ score,
                                             const int* __restrict__ target,
                                             const unsigned* __restrict__ pack,
                                             float* __restrict__ pr,
                                             float* __restrict__ la,
                                             float* __restrict__ cov) {
    int bid = blockIdx.x;
    int t = threadIdx.x;

    if (bid < NB_CE) {
        // ---- CE role: thread per 4 pixels ---------------------------------
        __shared__ float rn[4], rc[4];
        int tid = bid * 256 + t;
        int p0 = tid * 4;
        int n = p0 >> 18;
        int hw = p0 & (HW_ - 1);
        const float* sp = score + (size_t)n * C_ * HW_ + hw;
        int4 t4 = *(const int4*)(target + p0);

        float4 se = {0.f, 0.f, 0.f, 0.f};
        float4 stgt = {0.f, 0.f, 0.f, 0.f};
        float4 s[7];
#pragma unroll
        for (int cb = 0; cb < C_; cb += 7) {
#pragma unroll
            for (int u = 0; u < 7; ++u)
                s[u] = *(const float4*)(sp + (size_t)(cb + u) * HW_);
            __builtin_amdgcn_sched_barrier(0);   // 7 loads stay in flight
#pragma unroll
            for (int u = 0; u < 7; ++u) {
                int c = cb + u;
                se.x += __expf(s[u].x);
                se.y += __expf(s[u].y);
                se.z += __expf(s[u].z);
                se.w += __expf(s[u].w);
                if (t4.x == c) stgt.x = s[u].x;
                if (t4.y == c) stgt.y = s[u].y;
                if (t4.z == c) stgt.z = s[u].z;
                if (t4.w == c) stgt.w = s[u].w;
            }
        }
        float nll = 0.f, cnt = 0.f;
        if (t4.x != 255) { nll += __logf(se.x) - stgt.x; cnt += 1.f; }
        if (t4.y != 255) { nll += __logf(se.y) - stgt.y; cnt += 1.f; }
        if (t4.z != 255) { nll += __logf(se.z) - stgt.z; cnt += 1.f; }
        if (t4.w != 255) { nll += __logf(se.w) - stgt.w; cnt += 1.f; }

        nll = wave_sum(nll);
        cnt = wave_sum(cnt);
        int wv = t >> 6, lane = t & 63;
        if (lane == 0) { rn[wv] = nll; rc[wv] = cnt; }
        __syncthreads();
        if (t == 0)
            atomicAdd(&cov[NC_ * NCOV_ + 0], rn[0] + rn[1] + rn[2] + rn[3]);
        if (t == 64)
            atomicAdd(&cov[NC_ * NCOV_ + 1], rc[0] + rc[1] + rc[2] + rc[3]);
    } else {
        // ---- Pool role: thread per (n,c,i,g) ------------------------------
        int tid = (bid - NB_CE) * 256 + t;
        if (tid >= NC_ * P_ * G_) return;
        int g = tid % G_;
        int rest = tid / G_;
        int i = rest % P_;
        int ncidx = rest / P_;
        int n = ncidx / C_;
        int c = ncidx - n * C_;

        int hl = 3 * i - 1; if (hl < 0) hl = 0;
        int b = (g == 0) ? 0 : 12 * g - 4;
        int o3 = (b + 15 < W_) ? 12 : 8;

        const float* sb = score + (size_t)ncidx * HW_ + (size_t)hl * W_ + b;
        float f[3][16];
#pragma unroll
        for (int r = 0; r < 3; ++r) {
            const float* rp = sb + r * W_;
            float4 q0 = *(const float4*)(rp);
            float4 q1 = *(const float4*)(rp + 4);
            float4 q2 = *(const float4*)(rp + 8);
            float4 q3 = *(const float4*)(rp + o3);
            f[r][0] = q0.x;  f[r][1] = q0.y;  f[r][2] = q0.z;  f[r][3] = q0.w;
            f[r][4] = q1.x;  f[r][5] = q1.y;  f[r][6] = q1.z;  f[r][7] = q1.w;
            f[r][8] = q2.x;  f[r][9] = q2.y;  f[r][10] = q2.z; f[r][11] = q2.w;
            f[r][12] = q3.x; f[r][13] = q3.y; f[r][14] = q3.z; f[r][15] = q3.w;
        }

        const unsigned* pkp = pack + n * PP_ + i * P_ + 4 * g;
        size_t ob = (size_t)ncidx * PPAD_ + (size_t)i * PROW_ + 4 * g;
        if (g == 0) {
            do_cell<0>(f, pkp[0], c, pr + ob + 0, la + ob + 0);
            do_cell<2>(f, pkp[1], c, pr + ob + 1, la + ob + 1);
            do_cell<5>(f, pkp[2], c, pr + ob + 2, la + ob + 2);
            do_cell<8>(f, pkp[3], c, pr + ob + 3, la + ob + 3);
        } else {
            do_cell<3>(f, pkp[0], c, pr + ob + 0, la + ob + 0);
            do_cell<6>(f, pkp[1], c, pr + ob + 1, la + ob + 1);
            do_cell<9>(f, pkp[2], c, pr + ob + 2, la + ob + 2);
            if (4 * g + 3 < P_)
                do_cell<12>(f, pkp[3], c, pr + ob + 3, la + ob + 3);
        }
    }
}

// ---------------------------------------------------------------------------
// k_cov v4: 7 register-light parts (<=33 accumulators each). UNCHANGED.
//   z=0: la  s1[9] + SAA d<3 (24)     z=1: la  SAA d>=3 (21)
//   z=2: pr  s1[9] + SBB d<3 (24)     z=3: pr  SBB d>=3 (21)
//   z=4..6: SAB with a-row RA=z-4 (27 each)
// grid = (84, 6, 7), block = 256.
// ---------------------------------------------------------------------------
template <bool WITH_S1, int D0, int D1>
DEVINL void cov_tri(const float* __restrict__ X, float* __restrict__ cov,
                    int nc, int r0, int rend, int s1base, int s2base,
                    int tid, float (*red)[33]) {
    constexpr int NS2 = ((9 - D0) * (10 - D0) - (9 - D1) * (10 - D1)) / 2;
    constexpr int RLO = D0 / 3;
    constexpr int NS1 = WITH_S1 ? 9 : 0;
    constexpr int KOFF = tstart(D0);
    float s1[9], s2[NS2];
#pragma unroll
    for (int k = 0; k < 9; ++k) s1[k] = 0.f;
#pragma unroll
    for (int k = 0; k < NS2; ++k) s2[k] = 0.f;

    int nitems = (rend - r0) * G_;
    for (int idx = tid; idx < nitems; idx += 256) {
        int lr = idx / G_;
        int q = idx - lr * G_;
        int x0 = q * 4;
        const float* base = X + (size_t)(r0 + lr) * PROW_ + x0;
        float v[3][8];
#pragma unroll
        for (int r = RLO; r < 3; ++r) {
            float4 u0 = *(const float4*)(base + r * PROW_);
            float4 u1 = *(const float4*)(base + r * PROW_ + 4);
            v[r][0] = u0.x; v[r][1] = u0.y; v[r][2] = u0.z; v[r][3] = u0.w;
            v[r][4] = u1.x; v[r][5] = u1.y; v[r][6] = u1.z; v[r][7] = u1.w;
        }
#pragma unroll
        for (int p = 0; p < 4; ++p) {
            if (x0 + p < Q_) {
                if constexpr (WITH_S1) {
#pragma unroll
                    for (int d = 0; d < 9; ++d) s1[d] += v[d / 3][p + d % 3];
                }
                int k = 0;
#pragma unroll
                for (int d = D0; d < D1; ++d)
#pragma unroll
                    for (int e = d; e < 9; ++e) {
                        s2[k] += v[d / 3][p + d % 3] * v[e / 3][p + e % 3];
                        ++k;
                    }
            }
        }
    }

    int lane = tid & 63, wv = tid >> 6;
    if constexpr (WITH_S1) {
#pragma unroll
        for (int k = 0; k < 9; ++k) { float v2 = wave_sum(s1[k]); if (lane == 0) red[wv][k] = v2; }
    }
#pragma unroll
    for (int k = 0; k < NS2; ++k) { float v2 = wave_sum(s2[k]); if (lane == 0) red[wv][NS1 + k] = v2; }
    __syncthreads();
    for (int k = tid; k < NS1 + NS2; k += 256) {
        float v2 = red[0][k] + red[1][k] + red[2][k] + red[3][k];
        int dst = (WITH_S1 && k < 9) ? (s1base + k) : (s2base + KOFF + k - NS1);
        atomicAdd(&cov[nc * NCOV_ + dst], v2);
    }
}

template <int RA>
DEVINL void cov_ab(const float* __restrict__ A, const float* __restrict__ B,
                   float* __restrict__ cov, int nc, int r0, int rend,
                   int tid, float (*red)[33]) {
    float sab[27];
#pragma unroll
    for (int k = 0; k < 27; ++k) sab[k] = 0.f;

    int nitems = (rend - r0) * G_;
    for (int idx = tid; idx < nitems; idx += 256) {
        int lr = idx / G_;
        int q = idx - lr * G_;
        int x0 = q * 4;
        size_t off = (size_t)(r0 + lr) * PROW_ + x0;
        float a[8], b[3][8];
        {
            float4 u0 = *(const float4*)(A + off + RA * PROW_);
            float4 u1 = *(const float4*)(A + off + RA * PROW_ + 4);
            a[0] = u0.x; a[1] = u0.y; a[2] = u0.z; a[3] = u0.w;
            a[4] = u1.x; a[5] = u1.y; a[6] = u1.z; a[7] = u1.w;
        }
#pragma unroll
        for (int r = 0; r < 3; ++r) {
            float4 w0 = *(const float4*)(B + off + r * PROW_);
            float4 w1 = *(const float4*)(B + off + r * PROW_ + 4);
            b[r][0] = w0.x; b[r][1] = w0.y; b[r][2] = w0.z; b[r][3] = w0.w;
            b[r][4] = w1.x; b[r][5] = w1.y; b[r][6] = w1.z; b[r][7] = w1.w;
        }
#pragma unroll
        for (int p = 0; p < 4; ++p) {
            if (x0 + p < Q_) {
#pragma unroll
                for (int dm = 0; dm < 3; ++dm)
#pragma unroll
                    for (int e = 0; e < 9; ++e)
                        sab[dm * 9 + e] += a[p + dm] * b[e / 3][p + e % 3];
            }
        }
    }

    int lane = tid & 63, wv = tid >> 6;
#pragma unroll
    for (int k = 0; k < 27; ++k) { float v2 = wave_sum(sab[k]); if (lane == 0) red[wv][k] = v2; }
    __syncthreads();
    for (int k = tid; k < 27; k += 256) {
        float v2 = red[0][k] + red[1][k] + red[2][k] + red[3][k];
        atomicAdd(&cov[nc * NCOV_ + 108 + RA * 27 + k], v2);
    }
}

__global__ __launch_bounds__(256) void k_cov(const float* __restrict__ la,
                                             const float* __restrict__ pr,
                                             float* __restrict__ cov) {
    __shared__ float red[4][33];
    int nc = blockIdx.x;
    int chunk = blockIdx.y;
    int part = blockIdx.z;
    int r0 = chunk * RC_;
    int rend = r0 + RC_;
    if (rend > Q_) rend = Q_;
    int tid = threadIdx.x;
    const float* LA = la + (size_t)nc * PPAD_;
    const float* PR = pr + (size_t)nc * PPAD_;

    switch (part) {
        case 0: cov_tri<true, 0, 3>(LA, cov, nc, r0, rend, 0, 18, tid, red); break;
        case 1: cov_tri<false, 3, 9>(LA, cov, nc, r0, rend, 0, 18, tid, red); break;
        case 2: cov_tri<true, 0, 3>(PR, cov, nc, r0, rend, 9, 63, tid, red); break;
        case 3: cov_tri<false, 3, 9>(PR, cov, nc, r0, rend, 9, 63, tid, red); break;
        case 4: cov_ab<0>(LA, PR, cov, nc, r0, rend, tid, red); break;
        case 5: cov_ab<1>(LA, PR, cov, nc, r0, rend, tid, red); break;
        case 6: cov_ab<2>(LA, PR, cov, nc, r0, rend, tid, red); break;
    }
}

// ---------------------------------------------------------------------------
// k_final: per-(n,c) 9x9 algebra. UNCHANGED.
// ---------------------------------------------------------------------------
__global__ __launch_bounds__(128) void k_final(const float* __restrict__ cov,
                                               float* __restrict__ out) {
    __shared__ float red[128];
    int t = threadIdx.x;
    float my = 0.f;
    if (t < NC_) {
        const float* S = cov + t * NCOV_;
        const float Lf = (float)(Q_ * Q_);  // 28561
        float sA[9], sB[9];
#pragma unroll
        for (int d = 0; d < 9; ++d) { sA[d] = S[d]; sB[d] = S[9 + d]; }
        float laC[45], M[45], Cm[81];
        {
            int k = 0;
#pragma unroll
            for (int d = 0; d < 9; ++d)
#pragma unroll
                for (int e = d; e < 9; ++e) {
                    laC[k] = S[18 + k] - sA[d] * sA[e] / Lf;
                    M[k] = S[63 + k] - sB[d] * sB[e] / Lf + (d == e ? EPS_ : 0.f);
                    ++k;
                }
#pragma unroll
            for (int d = 0; d < 9; ++d)
#pragma unroll
                for (int e = 0; e < 9; ++e)
                    Cm[d * 9 + e] = S[108 + d * 9 + e] - sA[d] * sB[e] / Lf;
        }
#pragma unroll
        for (int j = 0; j < 9; ++j) {
            float s = M[tstart(j)];
#pragma unroll
            for (int k = 0; k < j; ++k) { float l = M[tstart(k) + (j - k)]; s -= l * l; }
            float dj = sqrtf(fmaxf(s, 1e-30f));
            M[tstart(j)] = dj;
            float inv = 1.f / dj;
#pragma unroll
            for (int i = j + 1; i < 9; ++i) {
                float s2 = M[tstart(j) + (i - j)];
#pragma unroll
                for (int k = 0; k < j; ++k)
                    s2 -= M[tstart(k) + (i - k)] * M[tstart(k) + (j - k)];
                M[tstart(j) + (i - j)] = s2 * inv;
            }
        }
#pragma unroll
        for (int p = 0; p < 9; ++p) {
#pragma unroll
            for (int i = 0; i < 9; ++i) {
                float s = Cm[p * 9 + i];
#pragma unroll
                for (int k = 0; k < i; ++k)
                    s -= M[tstart(k) + (i - k)] * Cm[p * 9 + k];
                Cm[p * 9 + i] = s / M[tstart(i)];
            }
        }
#pragma unroll
        for (int d = 0; d < 9; ++d)
#pragma unroll
            for (int e = d; e < 9; ++e) {
                float s = 0.f;
#pragma unroll
                for (int i = 0; i < 9; ++i) s += Cm[d * 9 + i] * Cm[e * 9 + i];
                laC[tstart(d) + (e - d)] -= s;
                if (d == e) laC[tstart(d)] += EPS_;
            }
        float rmi = 0.f;
#pragma unroll
        for (int j = 0; j < 9; ++j) {
            float s = laC[tstart(j)];
#pragma unroll
            for (int k = 0; k < j; ++k) { float l = laC[tstart(k) + (j - k)]; s -= l * l; }
            float dj = sqrtf(fmaxf(s, 0.f));
            laC[tstart(j)] = dj;
            float inv = 1.f / fmaxf(dj, 1e-30f);
#pragma unroll
            for (int i = j + 1; i < 9; ++i) {
                float s2 = laC[tstart(j) + (i - j)];
#pragma unroll
                for (int k = 0; k < j; ++k)
                    s2 -= laC[tstart(k) + (i - k)] * laC[tstart(k) + (j - k)];
                laC[tstart(j) + (i - j)] = s2 * inv;
            }
            rmi += __logf(dj + 1e-8f);
        }
        my = rmi;
    }
    red[t] = my;
    __syncthreads();
#pragma unroll
    for (int o = 64; o > 0; o >>= 1) {
        if (t < o) red[t] += red[t + o];
        __syncthreads();
    }
    if (t == 0) {
        float rmi_total = red[0] / 36.f;  // / (N * HALF_D)
        float ce = cov[NC_ * NCOV_ + 0] / cov[NC_ * NCOV_ + 1];
        out[0] = 0.5f * ce + 0.5f * rmi_total;
    }
}

extern "C" void kernel_launch(void* const* d_in, const int* in_sizes, int n_in,
                              void* d_out, int out_size, void* d_ws, size_t ws_size,
                              hipStream_t stream) {
    const float* score = (const float*)d_in[0];
    const int* target = (const int*)d_in[1];
    float* pr = (float*)d_ws;
    float* la = pr + (size_t)NC_ * PPAD_;
    float* cov = la + (size_t)NC_ * PPAD_;              // NC_*NCOV_ + 2 floats
    unsigned* pack = (unsigned*)(cov + NC_ * NCOV_ + 2);
    hipMemsetAsync(cov, 0, (size_t)(NC_ * NCOV_ + 2) * sizeof(float), stream);

    k_bits<<<dim3((N_ * PP_ + 255) / 256), dim3(256), 0, stream>>>(target, pack);
    k_mix<<<dim3(NB_CE + NB_PL), dim3(256), 0, stream>>>(score, target, pack, pr, la, cov);
    k_cov<<<dim3(NC_, 6, 7), dim3(256), 0, stream>>>(la, pr, cov);
    k_final<<<dim3(1), dim3(128), 0, stream>>>(cov, (float*)d_out);
}